// Round 5
// baseline (283.043 us; speedup 1.0000x reference)
//
#include <hip/hip_runtime.h>
#include <hip/hip_bf16.h>

// GCN: 3x GCNConv (sym-norm, self-loops) + linear head.
// N=50000 nodes, E=800000 edges, F: 128 -> 128 -> 128 -> 64 -> 1.
// Round 19 (resubmit; r19 bench hit GPUAcquisitionTimeout, never measured):
// overlap layer-1 GEMM with the CSR build. Fat kernel = gemm1 blocks
// [0,1564) + hist/wprep blocks [1564,1760). gemm1 is independent of the
// build; previously it ran serially after it while build kernels left ~75%
// of CUs idle. Dependencies resolved: (a) W1 bf16 planes produced by a tiny
// 64-block pre-kernel (gemm1's B operand); fat-wprep covers Wh/W2 only.
// (b) dis (scale) unavailable during gemm1 -> gemm1 writes UNSCALED planes;
// layer-1 aggregate applies dis[src] per gathered row in fp32 (exact mul of
// the bf16-rounded product; error same order as before, <=2^-10 rel).
// Kept: r18 aligned ws + 16-lane/16B gathers; r17 split-A; r16 ticket scan.
// Disproven: panels (r10/r11), phase fusion (r12), coop build (r14),
// gemm col-group serialization (r16).

#define N_NODES 50000
#define N_EDGES 800000
#define NBUCK 196
#define GB 196
#define EPB 4096
#define GEMM1ROWS ((N_NODES + 63) / 64)   // 782
#define GEMM1B (GEMM1ROWS * 2)            // 1564

typedef __attribute__((ext_vector_type(8))) short short8;
typedef __attribute__((ext_vector_type(8))) unsigned short ushort8v;
typedef __attribute__((ext_vector_type(4))) float f32x4;

static __device__ __forceinline__ unsigned short f2bf(float f) {
    __hip_bfloat16 h = __float2bfloat16(f);
    return *reinterpret_cast<unsigned short*>(&h);
}
static __device__ __forceinline__ float bf2f(unsigned short u) {
    return __uint_as_float(((unsigned)u) << 16);
}

// ---------- GEMM device body ----------
// SCALED: multiply C rows by scale[] (layers 2/3). !SCALED: write raw (gemm1).
template <int NOUT, bool SPLITA, bool SCALED>
static __device__ __forceinline__ void gemm_body(
    unsigned short* sAhi, unsigned short* sAlo, int bx, int by, int tid,
    const float* __restrict__ A,
    const unsigned short* __restrict__ Ahi, const unsigned short* __restrict__ Alo,
    const unsigned short* __restrict__ Wthi, const unsigned short* __restrict__ Wtlo,
    const float* __restrict__ scale, unsigned short* __restrict__ C, int M) {
    constexpr int LDK = 136;
    int w = tid >> 6, lane = tid & 63;
    int quad = lane >> 4, m = lane & 15;
    int Rbase = bx * 64, Cbase = by * 64;
    int r0 = (w & 1) * 32, c0 = (w >> 1) * 32;

    short8 bh[4][2], bl[4][2];
#pragma unroll
    for (int ks = 0; ks < 4; ++ks)
#pragma unroll
        for (int g = 0; g < 2; ++g) {
            size_t off = (size_t)(Cbase + c0 + g * 16 + m) * 128 + ks * 32 + quad * 8;
            bh[ks][g] = *(const short8*)(Wthi + off);
            bl[ks][g] = *(const short8*)(Wtlo + off);
        }

    if constexpr (SPLITA) {
        for (int i = tid; i < 64 * 16; i += 256) {
            int r = i >> 4, c8 = i & 15;
            int row = Rbase + r;
            short8 hv = {0,0,0,0,0,0,0,0}, lv = {0,0,0,0,0,0,0,0};
            if (row < M) {
                hv = *(const short8*)(Ahi + (size_t)row * 128 + c8 * 8);
                lv = *(const short8*)(Alo + (size_t)row * 128 + c8 * 8);
            }
            *(short8*)(sAhi + r * LDK + c8 * 8) = hv;
            *(short8*)(sAlo + r * LDK + c8 * 8) = lv;
        }
    } else {
        for (int i = tid; i < 64 * 32; i += 256) {
            int r = i >> 5, c4 = i & 31;
            int row = Rbase + r;
            float4 v = make_float4(0.f, 0.f, 0.f, 0.f);
            if (row < M) v = ((const float4*)(A + (size_t)row * 128))[c4];
            ushort4 hi, lo;
            hi.x = f2bf(v.x); lo.x = f2bf(v.x - bf2f(hi.x));
            hi.y = f2bf(v.y); lo.y = f2bf(v.y - bf2f(hi.y));
            hi.z = f2bf(v.z); lo.z = f2bf(v.z - bf2f(hi.z));
            hi.w = f2bf(v.w); lo.w = f2bf(v.w - bf2f(hi.w));
            *(ushort4*)(sAhi + r * LDK + c4 * 4) = hi;
            *(ushort4*)(sAlo + r * LDK + c4 * 4) = lo;
        }
    }
    __syncthreads();

    f32x4 z = {0.f, 0.f, 0.f, 0.f};
    f32x4 acc00 = z, acc01 = z, acc10 = z, acc11 = z;

#pragma unroll
    for (int ks = 0; ks < 4; ++ks) {
        int kof = ks * 32 + quad * 8;
        short8 ah0 = *(const short8*)(sAhi + (r0 + m) * LDK + kof);
        short8 ah1 = *(const short8*)(sAhi + (r0 + 16 + m) * LDK + kof);
        short8 al0 = *(const short8*)(sAlo + (r0 + m) * LDK + kof);
        short8 al1 = *(const short8*)(sAlo + (r0 + 16 + m) * LDK + kof);
        acc00 = __builtin_amdgcn_mfma_f32_16x16x32_bf16(ah0, bh[ks][0], acc00, 0, 0, 0);
        acc01 = __builtin_amdgcn_mfma_f32_16x16x32_bf16(ah0, bh[ks][1], acc01, 0, 0, 0);
        acc10 = __builtin_amdgcn_mfma_f32_16x16x32_bf16(ah1, bh[ks][0], acc10, 0, 0, 0);
        acc11 = __builtin_amdgcn_mfma_f32_16x16x32_bf16(ah1, bh[ks][1], acc11, 0, 0, 0);
        acc00 = __builtin_amdgcn_mfma_f32_16x16x32_bf16(ah0, bl[ks][0], acc00, 0, 0, 0);
        acc01 = __builtin_amdgcn_mfma_f32_16x16x32_bf16(ah0, bl[ks][1], acc01, 0, 0, 0);
        acc10 = __builtin_amdgcn_mfma_f32_16x16x32_bf16(ah1, bl[ks][0], acc10, 0, 0, 0);
        acc11 = __builtin_amdgcn_mfma_f32_16x16x32_bf16(ah1, bl[ks][1], acc11, 0, 0, 0);
        acc00 = __builtin_amdgcn_mfma_f32_16x16x32_bf16(al0, bh[ks][0], acc00, 0, 0, 0);
        acc01 = __builtin_amdgcn_mfma_f32_16x16x32_bf16(al0, bh[ks][1], acc01, 0, 0, 0);
        acc10 = __builtin_amdgcn_mfma_f32_16x16x32_bf16(al1, bh[ks][0], acc10, 0, 0, 0);
        acc11 = __builtin_amdgcn_mfma_f32_16x16x32_bf16(al1, bh[ks][1], acc11, 0, 0, 0);
    }

#pragma unroll
    for (int reg = 0; reg < 4; ++reg) {
        int row0g = Rbase + r0 + quad * 4 + reg;
        if (row0g < M) {
            float sc = SCALED ? scale[row0g] : 1.0f;
            C[(size_t)row0g * NOUT + Cbase + c0 + m]      = f2bf(acc00[reg] * sc);
            C[(size_t)row0g * NOUT + Cbase + c0 + 16 + m] = f2bf(acc01[reg] * sc);
        }
        int row1g = row0g + 16;
        if (row1g < M) {
            float sc = SCALED ? scale[row1g] : 1.0f;
            C[(size_t)row1g * NOUT + Cbase + c0 + m]      = f2bf(acc10[reg] * sc);
            C[(size_t)row1g * NOUT + Cbase + c0 + 16 + m] = f2bf(acc11[reg] * sc);
        }
    }
}

// ---------- W1 prep (gemm1's B operand; must precede the fat kernel) -------
__global__ __launch_bounds__(256) void w1prep_kernel(
    const float* __restrict__ W1,
    unsigned short* __restrict__ Hi, unsigned short* __restrict__ Lo) {
    int gt = blockIdx.x * 256 + threadIdx.x;  // [0, 16384)
    int col = gt & 127, k = gt >> 7;          // W1 is [128][128]
    float v = W1[gt];
    unsigned short hi = f2bf(v);
    unsigned short lo = f2bf(v - bf2f(hi));
    Hi[(size_t)col * 128 + k] = hi;
    Lo[(size_t)col * 128 + k] = lo;
}

// ---------- FAT kernel: gemm1 (unscaled) + hist + Wh/W2 prep ----------
__global__ __launch_bounds__(256) void fat_gemm1_hist_kernel(
    const float* __restrict__ x,
    const unsigned short* __restrict__ W1thi, const unsigned short* __restrict__ W1tlo,
    unsigned short* __restrict__ C,
    const int* __restrict__ dstv, int* __restrict__ H, int nE, int* __restrict__ ticket,
    const float* __restrict__ Wh, const float* __restrict__ W2,
    unsigned short* __restrict__ Whhi, unsigned short* __restrict__ Whlo,
    unsigned short* __restrict__ W2hi, unsigned short* __restrict__ W2lo) {
    constexpr int LDK = 136;
    __shared__ unsigned short sAhi[64 * LDK];
    __shared__ unsigned short sAlo[64 * LDK];

    int gb = blockIdx.x;
    if (gb < GEMM1B) {
        gemm_body<128, false, false>(sAhi, sAlo, gb >> 1, gb & 1, threadIdx.x,
                                     x, nullptr, nullptr, W1thi, W1tlo, nullptr, C, N_NODES);
        return;
    }
    int hb = gb - GEMM1B;  // [0, GB)

    if (hb == 0 && threadIdx.x == 0) *ticket = 0;
    int gt = hb * 256 + threadIdx.x;
    if (gt < 24576) {  // Wh (16384) then W2 (8192): transposed bf16 hi/lo
        const float* W; unsigned short *Hi, *Lo; int nout, lt;
        if (gt < 16384) { W = Wh; Hi = Whhi; Lo = Whlo; nout = 128; lt = gt; }
        else            { W = W2; Hi = W2hi; Lo = W2lo; nout = 64;  lt = gt - 16384; }
        int col = lt % nout, k = lt / nout;
        float v = W[lt];
        unsigned short hi = f2bf(v);
        unsigned short lo = f2bf(v - bf2f(hi));
        Hi[(size_t)col * 128 + k] = hi;
        Lo[(size_t)col * 128 + k] = lo;
    }

    int* h = (int*)sAhi;  // alias: 784 B inside 17 KB
    for (int i = threadIdx.x; i < NBUCK; i += 256) h[i] = 0;
    __syncthreads();
    int base = hb * EPB;
#pragma unroll
    for (int i = 0; i < EPB / 256; ++i) {
        int e = base + i * 256 + threadIdx.x;
        if (e < nE) atomicAdd(&h[dstv[e] >> 8], 1);
    }
    __syncthreads();
    for (int i = threadIdx.x; i < NBUCK; i += 256)
        H[i * GB + hb] = h[i];
}

// ---------- scan (ticket fold) ----------
__global__ __launch_bounds__(256) void scan_kernel(int* __restrict__ H,
                                                   int* __restrict__ bsum,
                                                   int* __restrict__ bstart,
                                                   int* __restrict__ rowoff_last,
                                                   int* __restrict__ ticket) {
    __shared__ int s[256];
    __shared__ int lastFlag;
    int t = threadIdx.x, k = blockIdx.x;
    int v = (t < GB) ? H[k * GB + t] : 0;
    s[t] = v;
    __syncthreads();
    for (int off = 1; off < 256; off <<= 1) {
        int u = (t >= off) ? s[t - off] : 0;
        __syncthreads();
        s[t] += u;
        __syncthreads();
    }
    if (t < GB) H[k * GB + t] = s[t] - v;
    if (t == 255) {
        bsum[k] = s[255];
        __threadfence();
        int tk = atomicAdd(ticket, 1);
        lastFlag = (tk == NBUCK - 1);
    }
    __syncthreads();
    if (!lastFlag) return;
    __threadfence();
    int v2 = (t < NBUCK) ? bsum[t] : 0;
    s[t] = v2;
    __syncthreads();
    for (int off = 1; off < 256; off <<= 1) {
        int u = (t >= off) ? s[t - off] : 0;
        __syncthreads();
        s[t] += u;
        __syncthreads();
    }
    if (t < NBUCK) bstart[t] = s[t] - v2;
    if (t == 0) { bstart[NBUCK] = N_EDGES; *rowoff_last = N_EDGES; }
}

__global__ __launch_bounds__(256) void partition_kernel(const int* __restrict__ srcv,
                                                        const int* __restrict__ dstv,
                                                        const int* __restrict__ H,
                                                        const int* __restrict__ bstart,
                                                        unsigned int* __restrict__ P, int nE) {
    __shared__ int cur[NBUCK];
    for (int i = threadIdx.x; i < NBUCK; i += 256)
        cur[i] = bstart[i] + H[i * GB + blockIdx.x];
    __syncthreads();
    int base = blockIdx.x * EPB;
#pragma unroll
    for (int i = 0; i < EPB / 256; ++i) {
        int e = base + i * 256 + threadIdx.x;
        if (e < nE) {
            int d = dstv[e];
            unsigned int pk = (unsigned int)srcv[e] | ((unsigned int)(d & 255) << 16);
            int pos = atomicAdd(&cur[d >> 8], 1);
            P[pos] = pk;
        }
    }
}

__global__ __launch_bounds__(256) void bucket_csr_kernel(const unsigned int* __restrict__ P,
                                                         const int* __restrict__ bstart,
                                                         int* __restrict__ rowoff,
                                                         float* __restrict__ dis,
                                                         unsigned short* __restrict__ csr_src, int n) {
    __shared__ int cnt[256];
    __shared__ int s[256];
    __shared__ int cur[256];
    int t = threadIdx.x, k = blockIdx.x;
    int ebeg = bstart[k], eend = bstart[k + 1];
    cnt[t] = 0;
    __syncthreads();
    for (int e = ebeg + t; e < eend; e += 256)
        atomicAdd(&cnt[(P[e] >> 16) & 255], 1);
    __syncthreads();
    int myc = cnt[t];
    s[t] = myc;
    __syncthreads();
    for (int off = 1; off < 256; off <<= 1) {
        int v = (t >= off) ? s[t - off] : 0;
        __syncthreads();
        s[t] += v;
        __syncthreads();
    }
    int excl = s[t] - myc;
    int node = (k << 8) + t;
    if (node < n) {
        rowoff[node] = ebeg + excl;
        dis[node] = rsqrtf((float)(myc + 1));
    }
    cur[t] = ebeg + excl;
    __syncthreads();
    for (int e = ebeg + t; e < eend; e += 256) {
        unsigned int p = P[e];
        int pos = atomicAdd(&cur[(p >> 16) & 255], 1);
        csr_src[pos] = (unsigned short)(p & 0xFFFFu);
    }
}

// ---------- standalone GEMM (layers 2,3) ----------
template <int NOUT, bool SPLITA>
__global__ __launch_bounds__(256) void gemm_mfma_kernel(
    const float* __restrict__ A,
    const unsigned short* __restrict__ Ahi, const unsigned short* __restrict__ Alo,
    const unsigned short* __restrict__ Wthi, const unsigned short* __restrict__ Wtlo,
    const float* __restrict__ scale, unsigned short* __restrict__ C, int M) {
    constexpr int LDK = 136;
    __shared__ unsigned short sAhi[64 * LDK];
    __shared__ unsigned short sAlo[64 * LDK];
    gemm_body<NOUT, SPLITA, true>(sAhi, sAlo, blockIdx.x, blockIdx.y, threadIdx.x,
                                  A, Ahi, Alo, Wthi, Wtlo, scale, C, M);
}

// ---------- Aggregation: 16 lanes x 16B rows, 2 nodes/wave ----------
// SRCSCALE: rows unscaled (fat-gemm1 output) -> multiply by dis[src] in fp32.
template <bool SRCSCALE>
__global__ __launch_bounds__(256) void aggregate128_kernel(
    const int* __restrict__ rowoff, const unsigned short* __restrict__ csr_src,
    const float* __restrict__ dis, const unsigned short* __restrict__ tp,
    const float* __restrict__ bias,
    unsigned short* __restrict__ outHi, unsigned short* __restrict__ outLo, int n) {
    int wid = (blockIdx.x * 256 + threadIdx.x) >> 6;
    int lane = threadIdx.x & 63;
    int sub = lane >> 4, lc = lane & 15;
    int n0 = wid * 2;
    if (n0 >= n) return;
    int n1 = n0 + 1;
    bool has1 = (n1 < n);

    float a0[8] = {0.f,0.f,0.f,0.f,0.f,0.f,0.f,0.f};
    float a1[8] = {0.f,0.f,0.f,0.f,0.f,0.f,0.f,0.f};

#define ROW128(node) (*(const ushort8v*)(tp + (size_t)(node) * 128 + lc * 8))
#define ACCS(a, u, s) { a[0] += bf2f(u[0]) * s; a[1] += bf2f(u[1]) * s; \
                        a[2] += bf2f(u[2]) * s; a[3] += bf2f(u[3]) * s; \
                        a[4] += bf2f(u[4]) * s; a[5] += bf2f(u[5]) * s; \
                        a[6] += bf2f(u[6]) * s; a[7] += bf2f(u[7]) * s; }
#define SC(node) (SRCSCALE ? dis[node] : 1.0f)

    if (sub == 0) { float s = SC(n0); ushort8v u = ROW128(n0); ACCS(a0, u, s); }
    else if (sub == 1 && has1) { float s = SC(n1); ushort8v u = ROW128(n1); ACCS(a1, u, s); }

    int mid = rowoff[n0 + 1];
    int i0 = rowoff[n0] + sub;
    int i1 = mid + sub;
    int end1 = has1 ? rowoff[n1 + 1] : mid;

    while (i0 + 12 < mid && i1 + 12 < end1) {
        int p0 = csr_src[i0], p1 = csr_src[i0 + 4], p2 = csr_src[i0 + 8], p3 = csr_src[i0 + 12];
        int q0 = csr_src[i1], q1 = csr_src[i1 + 4], q2 = csr_src[i1 + 8], q3 = csr_src[i1 + 12];
        float sp0 = SC(p0), sp1 = SC(p1), sp2 = SC(p2), sp3 = SC(p3);
        float sq0 = SC(q0), sq1 = SC(q1), sq2 = SC(q2), sq3 = SC(q3);
        ushort8v u0 = ROW128(p0), u1 = ROW128(p1), u2 = ROW128(p2), u3 = ROW128(p3);
        ushort8v v0 = ROW128(q0), v1 = ROW128(q1), v2 = ROW128(q2), v3 = ROW128(q3);
        ACCS(a0, u0, sp0); ACCS(a0, u1, sp1); ACCS(a0, u2, sp2); ACCS(a0, u3, sp3);
        ACCS(a1, v0, sq0); ACCS(a1, v1, sq1); ACCS(a1, v2, sq2); ACCS(a1, v3, sq3);
        i0 += 16; i1 += 16;
    }
    while (i0 + 4 < mid && i1 + 4 < end1) {
        int p0 = csr_src[i0], p1 = csr_src[i0 + 4];
        int q0 = csr_src[i1], q1 = csr_src[i1 + 4];
        float sp0 = SC(p0), sp1 = SC(p1), sq0 = SC(q0), sq1 = SC(q1);
        ushort8v u0 = ROW128(p0), u1 = ROW128(p1);
        ushort8v v0 = ROW128(q0), v1 = ROW128(q1);
        ACCS(a0, u0, sp0); ACCS(a0, u1, sp1);
        ACCS(a1, v0, sq0); ACCS(a1, v1, sq1);
        i0 += 8; i1 += 8;
    }
    for (; i0 + 4 < mid; i0 += 8) {
        int p0 = csr_src[i0], p1 = csr_src[i0 + 4];
        float sp0 = SC(p0), sp1 = SC(p1);
        ushort8v u0 = ROW128(p0), u1 = ROW128(p1);
        ACCS(a0, u0, sp0); ACCS(a0, u1, sp1);
    }
    for (; i0 < mid; i0 += 4) { int p = csr_src[i0]; float s = SC(p); ushort8v u = ROW128(p); ACCS(a0, u, s); }
    for (; i1 + 4 < end1; i1 += 8) {
        int q0 = csr_src[i1], q1 = csr_src[i1 + 4];
        float sq0 = SC(q0), sq1 = SC(q1);
        ushort8v v0 = ROW128(q0), v1 = ROW128(q1);
        ACCS(a1, v0, sq0); ACCS(a1, v1, sq1);
    }
    for (; i1 < end1; i1 += 4) { int q = csr_src[i1]; float s = SC(q); ushort8v v = ROW128(q); ACCS(a1, v, s); }
#undef ROW128
#undef ACCS
#undef SC

#pragma unroll
    for (int j = 0; j < 8; ++j) {
        a0[j] += __shfl_xor(a0[j], 16);
        a0[j] += __shfl_xor(a0[j], 32);
        a1[j] += __shfl_xor(a1[j], 16);
        a1[j] += __shfl_xor(a1[j], 32);
    }

    float* ap = (sub == 0) ? a0 : a1;
    int node = (sub == 0) ? n0 : n1;
    bool valid = (sub == 0) || (sub == 1 && has1);
    if (valid) {
        float dd = dis[node];
        float4 b0 = ((const float4*)bias)[lc * 2];
        float4 b1v = ((const float4*)bias)[lc * 2 + 1];
        float r[8];
        r[0] = fmaxf(ap[0] * dd + b0.x, 0.f);
        r[1] = fmaxf(ap[1] * dd + b0.y, 0.f);
        r[2] = fmaxf(ap[2] * dd + b0.z, 0.f);
        r[3] = fmaxf(ap[3] * dd + b0.w, 0.f);
        r[4] = fmaxf(ap[4] * dd + b1v.x, 0.f);
        r[5] = fmaxf(ap[5] * dd + b1v.y, 0.f);
        r[6] = fmaxf(ap[6] * dd + b1v.z, 0.f);
        r[7] = fmaxf(ap[7] * dd + b1v.w, 0.f);
        ushort8v hi, lo;
#pragma unroll
        for (int j = 0; j < 8; ++j) {
            hi[j] = f2bf(r[j]);
            lo[j] = f2bf(r[j] - bf2f(hi[j]));
        }
        *(ushort8v*)(outHi + (size_t)node * 128 + lc * 8) = hi;
        *(ushort8v*)(outLo + (size_t)node * 128 + lc * 8) = lo;
    }
}

// F=64 + fused head.
__global__ __launch_bounds__(256) void aggregate64_head_kernel(
    const int* __restrict__ rowoff, const unsigned short* __restrict__ csr_src,
    const float* __restrict__ dis, const unsigned short* __restrict__ tp,
    const float* __restrict__ bias, const float* __restrict__ Wout,
    const float* __restrict__ bout, float* __restrict__ hout,
    float* __restrict__ out, int n) {
    int wid = (blockIdx.x * 256 + threadIdx.x) >> 6;
    int lane = threadIdx.x & 63;
    int sub = lane >> 4, lc = lane & 15;
    int n0 = wid * 2;
    if (n0 >= n) return;
    int n1 = n0 + 1;
    bool has1 = (n1 < n);

    float a0[4] = {0.f,0.f,0.f,0.f};
    float a1[4] = {0.f,0.f,0.f,0.f};

#define ROW64(node) (*((const ushort4*)(tp + (size_t)(node) * 64 + lc * 4)))
#define ACC2(a, u) { a[0] += bf2f(u.x); a[1] += bf2f(u.y); a[2] += bf2f(u.z); a[3] += bf2f(u.w); }

    if (sub == 0) { ushort4 u = ROW64(n0); ACC2(a0, u); }
    else if (sub == 1 && has1) { ushort4 u = ROW64(n1); ACC2(a1, u); }

    int mid = rowoff[n0 + 1];
    int i0 = rowoff[n0] + sub;
    int i1 = mid + sub;
    int end1 = has1 ? rowoff[n1 + 1] : mid;

    while (i0 + 12 < mid && i1 + 12 < end1) {
        int p0 = csr_src[i0], p1 = csr_src[i0 + 4], p2 = csr_src[i0 + 8], p3 = csr_src[i0 + 12];
        int q0 = csr_src[i1], q1 = csr_src[i1 + 4], q2 = csr_src[i1 + 8], q3 = csr_src[i1 + 12];
        ushort4 u0 = ROW64(p0), u1 = ROW64(p1), u2 = ROW64(p2), u3 = ROW64(p3);
        ushort4 v0 = ROW64(q0), v1 = ROW64(q1), v2 = ROW64(q2), v3 = ROW64(q3);
        ACC2(a0, u0); ACC2(a0, u1); ACC2(a0, u2); ACC2(a0, u3);
        ACC2(a1, v0); ACC2(a1, v1); ACC2(a1, v2); ACC2(a1, v3);
        i0 += 16; i1 += 16;
    }
    while (i0 + 4 < mid && i1 + 4 < end1) {
        int p0 = csr_src[i0], p1 = csr_src[i0 + 4];
        int q0 = csr_src[i1], q1 = csr_src[i1 + 4];
        ushort4 u0 = ROW64(p0), u1 = ROW64(p1);
        ushort4 v0 = ROW64(q0), v1 = ROW64(q1);
        ACC2(a0, u0); ACC2(a0, u1);
        ACC2(a1, v0); ACC2(a1, v1);
        i0 += 8; i1 += 8;
    }
    for (; i0 < mid; i0 += 4) { ushort4 u = ROW64(csr_src[i0]); ACC2(a0, u); }
    for (; i1 < end1; i1 += 4) { ushort4 v = ROW64(csr_src[i1]); ACC2(a1, v); }
#undef ROW64
#undef ACC2

#pragma unroll
    for (int j = 0; j < 4; ++j) {
        a0[j] += __shfl_xor(a0[j], 16);
        a0[j] += __shfl_xor(a0[j], 32);
        a1[j] += __shfl_xor(a1[j], 16);
        a1[j] += __shfl_xor(a1[j], 32);
    }

    float* ap = (sub == 0) ? a0 : a1;
    int node = (sub == 0) ? n0 : n1;
    bool valid = (sub == 0) || (sub == 1 && has1);
    float4 hv = make_float4(0.f, 0.f, 0.f, 0.f);
    if (valid) {
        float dd = dis[node];
        float4 b = ((const float4*)bias)[lc];
        hv.x = ap[0] * dd + b.x;
        hv.y = ap[1] * dd + b.y;
        hv.z = ap[2] * dd + b.z;
        hv.w = ap[3] * dd + b.w;
        ((float4*)(hout + (size_t)node * 64))[lc] = hv;
    }
    float4 wv = ((const float4*)Wout)[lc];
    float p = valid ? (hv.x * wv.x + hv.y * wv.y + hv.z * wv.z + hv.w * wv.w) : 0.f;
#pragma unroll
    for (int off = 8; off > 0; off >>= 1) p += __shfl_xor(p, off);
    if (lc == 0 && valid) out[node] = p + bout[0];
}

extern "C" void kernel_launch(void* const* d_in, const int* in_sizes, int n_in,
                              void* d_out, int out_size, void* d_ws, size_t ws_size,
                              hipStream_t stream) {
    const float* x    = (const float*)d_in[0];
    const int*   ei   = (const int*)d_in[1];
    const float* W1   = (const float*)d_in[2];
    const float* b1   = (const float*)d_in[3];
    const float* Wh   = (const float*)d_in[4];
    const float* bh   = (const float*)d_in[5];
    const float* W2   = (const float*)d_in[6];
    const float* b2   = (const float*)d_in[7];
    const float* Wout = (const float*)d_in[8];
    const float* bout = (const float*)d_in[9];

    const int N = N_NODES;
    const int E = N_EDGES;
    const int* srcv = ei;
    const int* dstv = ei + E;

    float* out  = (float*)d_out;
    float* hout = (float*)d_out + N;

    char* ws = (char*)d_ws;
    auto alloc = [&](size_t bytes) -> char* {
        char* p = ws;
        ws += (bytes + 255) & ~(size_t)255;
        return p;
    };
    int*   H       = (int*)alloc(sizeof(int) * NBUCK * GB);
    int*   bsum    = (int*)alloc(sizeof(int) * NBUCK);
    int*   bstart  = (int*)alloc(sizeof(int) * (NBUCK + 1));
    int*   ticket  = (int*)alloc(sizeof(int) * 4);
    int*   rowoff  = (int*)alloc(sizeof(int) * (N + 1));
    unsigned int* P = (unsigned int*)alloc(sizeof(unsigned int) * E);
    unsigned short* csr_src = (unsigned short*)alloc(sizeof(unsigned short) * (E + 2));
    float* dis     = (float*)alloc(sizeof(float) * N);
    unsigned short* W1thi = (unsigned short*)alloc(sizeof(unsigned short) * 128 * 128);
    unsigned short* W1tlo = (unsigned short*)alloc(sizeof(unsigned short) * 128 * 128);
    unsigned short* Whthi = (unsigned short*)alloc(sizeof(unsigned short) * 128 * 128);
    unsigned short* Whtlo = (unsigned short*)alloc(sizeof(unsigned short) * 128 * 128);
    unsigned short* W2thi = (unsigned short*)alloc(sizeof(unsigned short) * 64 * 128);
    unsigned short* W2tlo = (unsigned short*)alloc(sizeof(unsigned short) * 64 * 128);
    unsigned short* bufT  = (unsigned short*)alloc(sizeof(unsigned short) * (size_t)N * 128);
    unsigned short* bufHi = (unsigned short*)alloc(sizeof(unsigned short) * (size_t)N * 128);
    unsigned short* bufLo = (unsigned short*)alloc(sizeof(unsigned short) * (size_t)N * 128);

    // --- W1 planes (gemm1's B; 64 blocks, ~2 us) ---
    w1prep_kernel<<<64, 256, 0, stream>>>(W1, W1thi, W1tlo);

    // --- FAT: gemm1 (unscaled) overlapped with hist + Wh/W2 prep ---
    fat_gemm1_hist_kernel<<<GEMM1B + GB, 256, 0, stream>>>(
        x, W1thi, W1tlo, bufT,
        dstv, H, E, ticket,
        Wh, W2, Whthi, Whtlo, W2thi, W2tlo);

    scan_kernel<<<NBUCK, 256, 0, stream>>>(H, bsum, bstart, rowoff + N, ticket);
    partition_kernel<<<GB, 256, 0, stream>>>(srcv, dstv, H, bstart, P, E);
    bucket_csr_kernel<<<NBUCK, 256, 0, stream>>>(P, bstart, rowoff, dis, csr_src, N);

    const int aggBlocks = ((N + 1) / 2 * 64 + 255) / 256;
    const int gemmRows = (N + 63) / 64;

    // --- layer 1: agg applies dis[src] per row (rows are unscaled) ---
    aggregate128_kernel<true><<<aggBlocks, 256, 0, stream>>>(
        rowoff, csr_src, dis, bufT, b1, bufHi, bufLo, N);

    // --- layer 2 ---
    gemm_mfma_kernel<128, true><<<dim3(gemmRows, 2), 256, 0, stream>>>(
        nullptr, bufHi, bufLo, Whthi, Whtlo, dis, bufT, N);
    aggregate128_kernel<false><<<aggBlocks, 256, 0, stream>>>(
        rowoff, csr_src, dis, bufT, bh, bufHi, bufLo, N);

    // --- layer 3 + head ---
    gemm_mfma_kernel<64, true><<<dim3(gemmRows, 1), 256, 0, stream>>>(
        nullptr, bufHi, bufLo, W2thi, W2tlo, dis, bufT, N);
    aggregate64_head_kernel<<<aggBlocks, 256, 0, stream>>>(
        rowoff, csr_src, dis, bufT, b2, Wout, bout, hout, out, N);
}

// Round 6
// 258.948 us; speedup vs baseline: 1.0931x; 1.0931x over previous
//
#include <hip/hip_runtime.h>
#include <hip/hip_bf16.h>

// GCN: 3x GCNConv (sym-norm, self-loops) + linear head.
// N=50000 nodes, E=800000 edges, F: 128 -> 128 -> 128 -> 64 -> 1.
// Round 20: (a) REVERT r19 fat fusion (measured +5us vs r18: SRCSCALE added
// per-edge work; 34KB-LDS gemm blocks throttled hist co-residency). Back to
// r18 launch structure (10 launches, best measured 277.9).
// (b) AGG REWRITE from counters (r19: agg=47.7us, 29% HBM, 35% VALU, 32% occ
// -> latency-bound, only 8 row-loads in flight/wave): one 16-lane subgroup
// per NODE (4 nodes/wave), 8-deep ILP walk = 32 rows in flight/wave (4x).
// No cross-subgroup reduce (lane owns its 8 cols), no joint-walk drains,
// sequential csr_src per subgroup. Same for agg64 (+head, 4-xor reduce).
// Kept: r18 aligned ws; r17 split-A planes + ushort csr_src; r16 ticket scan.
// Disproven: panels (r10/r11), phase fusion (r12), coop build (r14), gemm
// col-group serialization (r16), fat gemm1+build fusion (r19).

#define N_NODES 50000
#define N_EDGES 800000
#define NBUCK 196
#define GB 196
#define EPB 4096

typedef __attribute__((ext_vector_type(8))) short short8;
typedef __attribute__((ext_vector_type(8))) unsigned short ushort8v;
typedef __attribute__((ext_vector_type(4))) float f32x4;

static __device__ __forceinline__ unsigned short f2bf(float f) {
    __hip_bfloat16 h = __float2bfloat16(f);
    return *reinterpret_cast<unsigned short*>(&h);
}
static __device__ __forceinline__ float bf2f(unsigned short u) {
    return __uint_as_float(((unsigned)u) << 16);
}

// ---------- CSR build (r18 form) ----------
__global__ __launch_bounds__(256) void hist_wprep_kernel(
    const int* __restrict__ dstv, int* __restrict__ H, int nE, int* __restrict__ ticket,
    const float* __restrict__ W1, const float* __restrict__ Wh, const float* __restrict__ W2,
    unsigned short* __restrict__ W1hi, unsigned short* __restrict__ W1lo,
    unsigned short* __restrict__ Whhi, unsigned short* __restrict__ Whlo,
    unsigned short* __restrict__ W2hi, unsigned short* __restrict__ W2lo) {
    int gt = blockIdx.x * 256 + threadIdx.x;
    if (gt == 0) *ticket = 0;
    if (gt < 40960) {
        const float* W; unsigned short *Hi, *Lo; int nout, lt;
        if (gt < 16384)      { W = W1; Hi = W1hi; Lo = W1lo; nout = 128; lt = gt; }
        else if (gt < 32768) { W = Wh; Hi = Whhi; Lo = Whlo; nout = 128; lt = gt - 16384; }
        else                 { W = W2; Hi = W2hi; Lo = W2lo; nout = 64;  lt = gt - 32768; }
        int col = lt % nout, k = lt / nout;
        float v = W[lt];
        unsigned short hi = f2bf(v);
        unsigned short lo = f2bf(v - bf2f(hi));
        Hi[(size_t)col * 128 + k] = hi;
        Lo[(size_t)col * 128 + k] = lo;
    }

    __shared__ int h[NBUCK];
    for (int i = threadIdx.x; i < NBUCK; i += 256) h[i] = 0;
    __syncthreads();
    int base = blockIdx.x * EPB;
#pragma unroll
    for (int i = 0; i < EPB / 256; ++i) {
        int e = base + i * 256 + threadIdx.x;
        if (e < nE) atomicAdd(&h[dstv[e] >> 8], 1);
    }
    __syncthreads();
    for (int i = threadIdx.x; i < NBUCK; i += 256)
        H[i * GB + blockIdx.x] = h[i];
}

__global__ __launch_bounds__(256) void scan_kernel(int* __restrict__ H,
                                                   int* __restrict__ bsum,
                                                   int* __restrict__ bstart,
                                                   int* __restrict__ rowoff_last,
                                                   int* __restrict__ ticket) {
    __shared__ int s[256];
    __shared__ int lastFlag;
    int t = threadIdx.x, k = blockIdx.x;
    int v = (t < GB) ? H[k * GB + t] : 0;
    s[t] = v;
    __syncthreads();
    for (int off = 1; off < 256; off <<= 1) {
        int u = (t >= off) ? s[t - off] : 0;
        __syncthreads();
        s[t] += u;
        __syncthreads();
    }
    if (t < GB) H[k * GB + t] = s[t] - v;
    if (t == 255) {
        bsum[k] = s[255];
        __threadfence();
        int tk = atomicAdd(ticket, 1);
        lastFlag = (tk == NBUCK - 1);
    }
    __syncthreads();
    if (!lastFlag) return;
    __threadfence();
    int v2 = (t < NBUCK) ? bsum[t] : 0;
    s[t] = v2;
    __syncthreads();
    for (int off = 1; off < 256; off <<= 1) {
        int u = (t >= off) ? s[t - off] : 0;
        __syncthreads();
        s[t] += u;
        __syncthreads();
    }
    if (t < NBUCK) bstart[t] = s[t] - v2;
    if (t == 0) { bstart[NBUCK] = N_EDGES; *rowoff_last = N_EDGES; }
}

__global__ __launch_bounds__(256) void partition_kernel(const int* __restrict__ srcv,
                                                        const int* __restrict__ dstv,
                                                        const int* __restrict__ H,
                                                        const int* __restrict__ bstart,
                                                        unsigned int* __restrict__ P, int nE) {
    __shared__ int cur[NBUCK];
    for (int i = threadIdx.x; i < NBUCK; i += 256)
        cur[i] = bstart[i] + H[i * GB + blockIdx.x];
    __syncthreads();
    int base = blockIdx.x * EPB;
#pragma unroll
    for (int i = 0; i < EPB / 256; ++i) {
        int e = base + i * 256 + threadIdx.x;
        if (e < nE) {
            int d = dstv[e];
            unsigned int pk = (unsigned int)srcv[e] | ((unsigned int)(d & 255) << 16);
            int pos = atomicAdd(&cur[d >> 8], 1);
            P[pos] = pk;
        }
    }
}

__global__ __launch_bounds__(256) void bucket_csr_kernel(const unsigned int* __restrict__ P,
                                                         const int* __restrict__ bstart,
                                                         int* __restrict__ rowoff,
                                                         float* __restrict__ dis,
                                                         unsigned short* __restrict__ csr_src, int n) {
    __shared__ int cnt[256];
    __shared__ int s[256];
    __shared__ int cur[256];
    int t = threadIdx.x, k = blockIdx.x;
    int ebeg = bstart[k], eend = bstart[k + 1];
    cnt[t] = 0;
    __syncthreads();
    for (int e = ebeg + t; e < eend; e += 256)
        atomicAdd(&cnt[(P[e] >> 16) & 255], 1);
    __syncthreads();
    int myc = cnt[t];
    s[t] = myc;
    __syncthreads();
    for (int off = 1; off < 256; off <<= 1) {
        int v = (t >= off) ? s[t - off] : 0;
        __syncthreads();
        s[t] += v;
        __syncthreads();
    }
    int excl = s[t] - myc;
    int node = (k << 8) + t;
    if (node < n) {
        rowoff[node] = ebeg + excl;
        dis[node] = rsqrtf((float)(myc + 1));
    }
    cur[t] = ebeg + excl;
    __syncthreads();
    for (int e = ebeg + t; e < eend; e += 256) {
        unsigned int p = P[e];
        int pos = atomicAdd(&cur[(p >> 16) & 255], 1);
        csr_src[pos] = (unsigned short)(p & 0xFFFFu);
    }
}

// ---------- MFMA GEMM: C[r] = bf16((A[r] @ W) * scale[r]) ----------
template <int NOUT, bool SPLITA>
__global__ __launch_bounds__(256) void gemm_mfma_kernel(
    const float* __restrict__ A,
    const unsigned short* __restrict__ Ahi, const unsigned short* __restrict__ Alo,
    const unsigned short* __restrict__ Wthi, const unsigned short* __restrict__ Wtlo,
    const float* __restrict__ scale, unsigned short* __restrict__ C, int M) {
    constexpr int LDK = 136;
    __shared__ unsigned short sAhi[64 * LDK];
    __shared__ unsigned short sAlo[64 * LDK];

    int tid = threadIdx.x;
    int w = tid >> 6, lane = tid & 63;
    int quad = lane >> 4, m = lane & 15;
    int Rbase = blockIdx.x * 64, Cbase = blockIdx.y * 64;
    int r0 = (w & 1) * 32, c0 = (w >> 1) * 32;

    short8 bh[4][2], bl[4][2];
#pragma unroll
    for (int ks = 0; ks < 4; ++ks)
#pragma unroll
        for (int g = 0; g < 2; ++g) {
            size_t off = (size_t)(Cbase + c0 + g * 16 + m) * 128 + ks * 32 + quad * 8;
            bh[ks][g] = *(const short8*)(Wthi + off);
            bl[ks][g] = *(const short8*)(Wtlo + off);
        }

    if constexpr (SPLITA) {
        for (int i = tid; i < 64 * 16; i += 256) {
            int r = i >> 4, c8 = i & 15;
            int row = Rbase + r;
            short8 hv = {0,0,0,0,0,0,0,0}, lv = {0,0,0,0,0,0,0,0};
            if (row < M) {
                hv = *(const short8*)(Ahi + (size_t)row * 128 + c8 * 8);
                lv = *(const short8*)(Alo + (size_t)row * 128 + c8 * 8);
            }
            *(short8*)(sAhi + r * LDK + c8 * 8) = hv;
            *(short8*)(sAlo + r * LDK + c8 * 8) = lv;
        }
    } else {
        for (int i = tid; i < 64 * 32; i += 256) {
            int r = i >> 5, c4 = i & 31;
            int row = Rbase + r;
            float4 v = make_float4(0.f, 0.f, 0.f, 0.f);
            if (row < M) v = ((const float4*)(A + (size_t)row * 128))[c4];
            ushort4 hi, lo;
            hi.x = f2bf(v.x); lo.x = f2bf(v.x - bf2f(hi.x));
            hi.y = f2bf(v.y); lo.y = f2bf(v.y - bf2f(hi.y));
            hi.z = f2bf(v.z); lo.z = f2bf(v.z - bf2f(hi.z));
            hi.w = f2bf(v.w); lo.w = f2bf(v.w - bf2f(hi.w));
            *(ushort4*)(sAhi + r * LDK + c4 * 4) = hi;
            *(ushort4*)(sAlo + r * LDK + c4 * 4) = lo;
        }
    }
    __syncthreads();

    f32x4 z = {0.f, 0.f, 0.f, 0.f};
    f32x4 acc00 = z, acc01 = z, acc10 = z, acc11 = z;

#pragma unroll
    for (int ks = 0; ks < 4; ++ks) {
        int kof = ks * 32 + quad * 8;
        short8 ah0 = *(const short8*)(sAhi + (r0 + m) * LDK + kof);
        short8 ah1 = *(const short8*)(sAhi + (r0 + 16 + m) * LDK + kof);
        short8 al0 = *(const short8*)(sAlo + (r0 + m) * LDK + kof);
        short8 al1 = *(const short8*)(sAlo + (r0 + 16 + m) * LDK + kof);
        acc00 = __builtin_amdgcn_mfma_f32_16x16x32_bf16(ah0, bh[ks][0], acc00, 0, 0, 0);
        acc01 = __builtin_amdgcn_mfma_f32_16x16x32_bf16(ah0, bh[ks][1], acc01, 0, 0, 0);
        acc10 = __builtin_amdgcn_mfma_f32_16x16x32_bf16(ah1, bh[ks][0], acc10, 0, 0, 0);
        acc11 = __builtin_amdgcn_mfma_f32_16x16x32_bf16(ah1, bh[ks][1], acc11, 0, 0, 0);
        acc00 = __builtin_amdgcn_mfma_f32_16x16x32_bf16(ah0, bl[ks][0], acc00, 0, 0, 0);
        acc01 = __builtin_amdgcn_mfma_f32_16x16x32_bf16(ah0, bl[ks][1], acc01, 0, 0, 0);
        acc10 = __builtin_amdgcn_mfma_f32_16x16x32_bf16(ah1, bl[ks][0], acc10, 0, 0, 0);
        acc11 = __builtin_amdgcn_mfma_f32_16x16x32_bf16(ah1, bl[ks][1], acc11, 0, 0, 0);
        acc00 = __builtin_amdgcn_mfma_f32_16x16x32_bf16(al0, bh[ks][0], acc00, 0, 0, 0);
        acc01 = __builtin_amdgcn_mfma_f32_16x16x32_bf16(al0, bh[ks][1], acc01, 0, 0, 0);
        acc10 = __builtin_amdgcn_mfma_f32_16x16x32_bf16(al1, bh[ks][0], acc10, 0, 0, 0);
        acc11 = __builtin_amdgcn_mfma_f32_16x16x32_bf16(al1, bh[ks][1], acc11, 0, 0, 0);
    }

#pragma unroll
    for (int reg = 0; reg < 4; ++reg) {
        int row0g = Rbase + r0 + quad * 4 + reg;
        if (row0g < M) {
            float sc = scale[row0g];
            C[(size_t)row0g * NOUT + Cbase + c0 + m]      = f2bf(acc00[reg] * sc);
            C[(size_t)row0g * NOUT + Cbase + c0 + 16 + m] = f2bf(acc01[reg] * sc);
        }
        int row1g = row0g + 16;
        if (row1g < M) {
            float sc = scale[row1g];
            C[(size_t)row1g * NOUT + Cbase + c0 + m]      = f2bf(acc10[reg] * sc);
            C[(size_t)row1g * NOUT + Cbase + c0 + 16 + m] = f2bf(acc11[reg] * sc);
        }
    }
}

// ---------- Aggregation: ONE 16-lane subgroup per node, 8-deep ILP ---------
// 4 nodes/wave, 32 row-loads in flight/wave (was 8). No cross-lane reduce:
// each lane owns its 8 columns for the whole walk. Sequential csr_src reads.
__global__ __launch_bounds__(256) void aggregate128_kernel(
    const int* __restrict__ rowoff, const unsigned short* __restrict__ csr_src,
    const float* __restrict__ dis, const unsigned short* __restrict__ tp,
    const float* __restrict__ bias,
    unsigned short* __restrict__ outHi, unsigned short* __restrict__ outLo, int n) {
    int gt = blockIdx.x * 256 + threadIdx.x;
    int node = gt >> 4;
    if (node >= n) return;
    int lc = gt & 15;

    float a[8] = {0.f,0.f,0.f,0.f,0.f,0.f,0.f,0.f};

#define ROW128(nd) (*(const ushort8v*)(tp + (size_t)(nd) * 128 + lc * 8))
#define ACC(u) { a[0] += bf2f(u[0]); a[1] += bf2f(u[1]); a[2] += bf2f(u[2]); a[3] += bf2f(u[3]); \
                 a[4] += bf2f(u[4]); a[5] += bf2f(u[5]); a[6] += bf2f(u[6]); a[7] += bf2f(u[7]); }

    { ushort8v u = ROW128(node); ACC(u); }  // self loop

    int i = rowoff[node], end = rowoff[node + 1];
    for (; i + 8 <= end; i += 8) {
        int p0 = csr_src[i],     p1 = csr_src[i + 1], p2 = csr_src[i + 2], p3 = csr_src[i + 3];
        int p4 = csr_src[i + 4], p5 = csr_src[i + 5], p6 = csr_src[i + 6], p7 = csr_src[i + 7];
        ushort8v u0 = ROW128(p0), u1 = ROW128(p1), u2 = ROW128(p2), u3 = ROW128(p3);
        ushort8v u4 = ROW128(p4), u5 = ROW128(p5), u6 = ROW128(p6), u7 = ROW128(p7);
        ACC(u0); ACC(u1); ACC(u2); ACC(u3); ACC(u4); ACC(u5); ACC(u6); ACC(u7);
    }
    if (i + 4 <= end) {
        int p0 = csr_src[i], p1 = csr_src[i + 1], p2 = csr_src[i + 2], p3 = csr_src[i + 3];
        ushort8v u0 = ROW128(p0), u1 = ROW128(p1), u2 = ROW128(p2), u3 = ROW128(p3);
        ACC(u0); ACC(u1); ACC(u2); ACC(u3);
        i += 4;
    }
    if (i + 2 <= end) {
        int p0 = csr_src[i], p1 = csr_src[i + 1];
        ushort8v u0 = ROW128(p0), u1 = ROW128(p1);
        ACC(u0); ACC(u1);
        i += 2;
    }
    if (i < end) { ushort8v u = ROW128(csr_src[i]); ACC(u); }
#undef ROW128
#undef ACC

    float dd = dis[node];
    float4 b0 = ((const float4*)bias)[lc * 2];
    float4 b1 = ((const float4*)bias)[lc * 2 + 1];
    float r[8];
    r[0] = fmaxf(a[0] * dd + b0.x, 0.f);
    r[1] = fmaxf(a[1] * dd + b0.y, 0.f);
    r[2] = fmaxf(a[2] * dd + b0.z, 0.f);
    r[3] = fmaxf(a[3] * dd + b0.w, 0.f);
    r[4] = fmaxf(a[4] * dd + b1.x, 0.f);
    r[5] = fmaxf(a[5] * dd + b1.y, 0.f);
    r[6] = fmaxf(a[6] * dd + b1.z, 0.f);
    r[7] = fmaxf(a[7] * dd + b1.w, 0.f);
    ushort8v hi, lo;
#pragma unroll
    for (int j = 0; j < 8; ++j) {
        hi[j] = f2bf(r[j]);
        lo[j] = f2bf(r[j] - bf2f(hi[j]));
    }
    *(ushort8v*)(outHi + (size_t)node * 128 + lc * 8) = hi;
    *(ushort8v*)(outLo + (size_t)node * 128 + lc * 8) = lo;
}

// F=64 + fused head: 16-lane subgroup per node, ushort4 (8 B) rows, 8-deep.
__global__ __launch_bounds__(256) void aggregate64_head_kernel(
    const int* __restrict__ rowoff, const unsigned short* __restrict__ csr_src,
    const float* __restrict__ dis, const unsigned short* __restrict__ tp,
    const float* __restrict__ bias, const float* __restrict__ Wout,
    const float* __restrict__ bout, float* __restrict__ hout,
    float* __restrict__ out, int n) {
    int gt = blockIdx.x * 256 + threadIdx.x;
    int node = gt >> 4;
    if (node >= n) return;
    int lc = gt & 15;

    float a[4] = {0.f,0.f,0.f,0.f};

#define ROW64(nd) (*((const ushort4*)(tp + (size_t)(nd) * 64 + lc * 4)))
#define ACC2(u) { a[0] += bf2f(u.x); a[1] += bf2f(u.y); a[2] += bf2f(u.z); a[3] += bf2f(u.w); }

    { ushort4 u = ROW64(node); ACC2(u); }  // self loop

    int i = rowoff[node], end = rowoff[node + 1];
    for (; i + 8 <= end; i += 8) {
        int p0 = csr_src[i],     p1 = csr_src[i + 1], p2 = csr_src[i + 2], p3 = csr_src[i + 3];
        int p4 = csr_src[i + 4], p5 = csr_src[i + 5], p6 = csr_src[i + 6], p7 = csr_src[i + 7];
        ushort4 u0 = ROW64(p0), u1 = ROW64(p1), u2 = ROW64(p2), u3 = ROW64(p3);
        ushort4 u4 = ROW64(p4), u5 = ROW64(p5), u6 = ROW64(p6), u7 = ROW64(p7);
        ACC2(u0); ACC2(u1); ACC2(u2); ACC2(u3); ACC2(u4); ACC2(u5); ACC2(u6); ACC2(u7);
    }
    if (i + 4 <= end) {
        int p0 = csr_src[i], p1 = csr_src[i + 1], p2 = csr_src[i + 2], p3 = csr_src[i + 3];
        ushort4 u0 = ROW64(p0), u1 = ROW64(p1), u2 = ROW64(p2), u3 = ROW64(p3);
        ACC2(u0); ACC2(u1); ACC2(u2); ACC2(u3);
        i += 4;
    }
    if (i + 2 <= end) {
        int p0 = csr_src[i], p1 = csr_src[i + 1];
        ushort4 u0 = ROW64(p0), u1 = ROW64(p1);
        ACC2(u0); ACC2(u1);
        i += 2;
    }
    if (i < end) { ushort4 u = ROW64(csr_src[i]); ACC2(u); }
#undef ROW64
#undef ACC2

    float dd = dis[node];
    float4 b = ((const float4*)bias)[lc];
    float4 hv;
    hv.x = a[0] * dd + b.x;
    hv.y = a[1] * dd + b.y;
    hv.z = a[2] * dd + b.z;
    hv.w = a[3] * dd + b.w;
    ((float4*)(hout + (size_t)node * 64))[lc] = hv;

    float4 wv = ((const float4*)Wout)[lc];
    float p = hv.x * wv.x + hv.y * wv.y + hv.z * wv.z + hv.w * wv.w;
#pragma unroll
    for (int off = 8; off > 0; off >>= 1) p += __shfl_xor(p, off);  // within subgroup
    if (lc == 0) out[node] = p + bout[0];
}

extern "C" void kernel_launch(void* const* d_in, const int* in_sizes, int n_in,
                              void* d_out, int out_size, void* d_ws, size_t ws_size,
                              hipStream_t stream) {
    const float* x    = (const float*)d_in[0];
    const int*   ei   = (const int*)d_in[1];
    const float* W1   = (const float*)d_in[2];
    const float* b1   = (const float*)d_in[3];
    const float* Wh   = (const float*)d_in[4];
    const float* bh   = (const float*)d_in[5];
    const float* W2   = (const float*)d_in[6];
    const float* b2   = (const float*)d_in[7];
    const float* Wout = (const float*)d_in[8];
    const float* bout = (const float*)d_in[9];

    const int N = N_NODES;
    const int E = N_EDGES;
    const int* srcv = ei;
    const int* dstv = ei + E;

    float* out  = (float*)d_out;
    float* hout = (float*)d_out + N;

    char* ws = (char*)d_ws;
    auto alloc = [&](size_t bytes) -> char* {
        char* p = ws;
        ws += (bytes + 255) & ~(size_t)255;
        return p;
    };
    int*   H       = (int*)alloc(sizeof(int) * NBUCK * GB);
    int*   bsum    = (int*)alloc(sizeof(int) * NBUCK);
    int*   bstart  = (int*)alloc(sizeof(int) * (NBUCK + 1));
    int*   ticket  = (int*)alloc(sizeof(int) * 4);
    int*   rowoff  = (int*)alloc(sizeof(int) * (N + 1));
    unsigned int* P = (unsigned int*)alloc(sizeof(unsigned int) * E);
    unsigned short* csr_src = (unsigned short*)alloc(sizeof(unsigned short) * (E + 8));
    float* dis     = (float*)alloc(sizeof(float) * N);
    unsigned short* W1thi = (unsigned short*)alloc(sizeof(unsigned short) * 128 * 128);
    unsigned short* W1tlo = (unsigned short*)alloc(sizeof(unsigned short) * 128 * 128);
    unsigned short* Whthi = (unsigned short*)alloc(sizeof(unsigned short) * 128 * 128);
    unsigned short* Whtlo = (unsigned short*)alloc(sizeof(unsigned short) * 128 * 128);
    unsigned short* W2thi = (unsigned short*)alloc(sizeof(unsigned short) * 64 * 128);
    unsigned short* W2tlo = (unsigned short*)alloc(sizeof(unsigned short) * 64 * 128);
    unsigned short* bufT  = (unsigned short*)alloc(sizeof(unsigned short) * (size_t)N * 128);
    unsigned short* bufHi = (unsigned short*)alloc(sizeof(unsigned short) * (size_t)N * 128);
    unsigned short* bufLo = (unsigned short*)alloc(sizeof(unsigned short) * (size_t)N * 128);

    // --- CSR build ---
    hist_wprep_kernel<<<GB, 256, 0, stream>>>(dstv, H, E, ticket,
                                              W1, Wh, W2, W1thi, W1tlo, Whthi, Whtlo, W2thi, W2tlo);
    scan_kernel<<<NBUCK, 256, 0, stream>>>(H, bsum, bstart, rowoff + N, ticket);
    partition_kernel<<<GB, 256, 0, stream>>>(srcv, dstv, H, bstart, P, E);
    bucket_csr_kernel<<<NBUCK, 256, 0, stream>>>(P, bstart, rowoff, dis, csr_src, N);

    const int aggBlocks = (N * 16 + 255) / 256;  // 16 lanes per node
    const int gemmRows = (N + 63) / 64;          // 782

    // --- layer 1 ---
    gemm_mfma_kernel<128, false><<<dim3(gemmRows, 2), 256, 0, stream>>>(
        x, nullptr, nullptr, W1thi, W1tlo, dis, bufT, N);
    aggregate128_kernel<<<aggBlocks, 256, 0, stream>>>(
        rowoff, csr_src, dis, bufT, b1, bufHi, bufLo, N);

    // --- layer 2 ---
    gemm_mfma_kernel<128, true><<<dim3(gemmRows, 2), 256, 0, stream>>>(
        nullptr, bufHi, bufLo, Whthi, Whtlo, dis, bufT, N);
    aggregate128_kernel<<<aggBlocks, 256, 0, stream>>>(
        rowoff, csr_src, dis, bufT, bh, bufHi, bufLo, N);

    // --- layer 3 + head ---
    gemm_mfma_kernel<64, true><<<dim3(gemmRows, 1), 256, 0, stream>>>(
        nullptr, bufHi, bufLo, W2thi, W2tlo, dis, bufT, N);
    aggregate64_head_kernel<<<aggBlocks, 256, 0, stream>>>(
        rowoff, csr_src, dis, bufT, b2, Wout, bout, hout, out, N);
}